// Round 1
// baseline (350.581 us; speedup 1.0000x reference)
//
#include <hip/hip_runtime.h>
#include <stdint.h>

#define NN   50000
#define DIMK 512
#define HIDN 256
#define NE   800000

typedef float f32x4 __attribute__((ext_vector_type(4)));
typedef short s16x8 __attribute__((ext_vector_type(8)));

static __device__ __forceinline__ unsigned short f2bf(float f) {
  union { float f; uint32_t u; } v; v.f = f;
  uint32_t u = v.u;
  u += 0x7fffu + ((u >> 16) & 1u);   // RNE
  return (unsigned short)(u >> 16);
}

// ---------------- degree histogram ----------------
__global__ void k_hist(const int* __restrict__ edst, int* __restrict__ cnt) {
  int e = blockIdx.x * 256 + threadIdx.x;
  if (e < NE) atomicAdd(&cnt[edst[e]], 1);
}

// ---------------- scan: offsets, cursor, dis ----------------
__global__ __launch_bounds__(1024) void k_scan(const int* __restrict__ cnt,
                                               int* __restrict__ offsets,
                                               int* __restrict__ cursor,
                                               float* __restrict__ dis) {
  __shared__ int part[1024];
  const int t = threadIdx.x;
  const int PER = 49;                 // 1024*49 = 50176 >= 50000
  const int base = t * PER;
  int s = 0;
  for (int j = 0; j < PER; ++j) { int i = base + j; if (i < NN) s += cnt[i]; }
  part[t] = s;
  __syncthreads();
  for (int o = 1; o < 1024; o <<= 1) {
    int v = 0;
    if (t >= o) v = part[t - o];
    __syncthreads();
    if (t >= o) part[t] += v;
    __syncthreads();
  }
  int run = part[t] - s;              // exclusive prefix
  for (int j = 0; j < PER; ++j) {
    int i = base + j;
    if (i < NN) {
      int c = cnt[i];
      offsets[i] = run;
      cursor[i]  = run;
      dis[i] = rsqrtf((float)(c + 1));   // +1 self loop
      run += c;
    }
  }
  if (t == 1023) offsets[NN] = part[1023];
}

// ---------------- CSR scatter ----------------
__global__ void k_scatter(const int* __restrict__ esrc, const int* __restrict__ edst,
                          int* __restrict__ cursor, int* __restrict__ ssorted) {
  int e = blockIdx.x * 256 + threadIdx.x;
  if (e < NE) {
    int d = edst[e];
    int p = atomicAdd(&cursor[d], 1);
    ssorted[p] = esrc[e];
  }
}

// ---------------- W1^T -> bf16, pre-swizzled per-kstep LDS image ----------------
// image for kstep t (16KB): element (k=32t+8g+i, col c) at byte
//   t*16384 + c*64 + ((g ^ ((c>>1)&3))<<4) + 2*i
__global__ void k_prep_w1t(const float* __restrict__ W1, char* __restrict__ w1t) {
  int tid = blockIdx.x * 256 + threadIdx.x;   // 512*256 = 131072 = DIMK*HIDN
  int c  = tid & 255;
  int k  = tid >> 8;
  int tt = k >> 5;
  int kk = k & 31;
  int g  = kk >> 3;
  int i  = kk & 7;
  unsigned short v = f2bf(W1[k * HIDN + c]);
  int byte = tt * 16384 + c * 64 + ((g ^ ((c >> 1) & 3)) << 4) + i * 2;
  *(unsigned short*)(w1t + byte) = v;
}

// ---------------- GEMM1: h1s = bf16(dis[row] * (x @ W1)) ----------------
// block: 4 waves, 64 rows x 256 cols; BK=32; dbuf LDS B-tile; A from global.
__global__ __launch_bounds__(256) void k_gemm1(const float* __restrict__ x,
                                               const char* __restrict__ w1t,
                                               const float* __restrict__ dis,
                                               unsigned short* __restrict__ h1s) {
  __shared__ char lds[32768];
  const int tid = threadIdx.x;
  const int l = tid & 63;
  const int r = l & 15;
  const int g = l >> 4;
  const int rowbase = blockIdx.x * 64 + (tid >> 6) * 16;
  int arow = rowbase + r;
  if (arow >= NN) arow = NN - 1;      // clamp; stores are guarded

  const char* gb = w1t + tid * 16;

  s16x8 Rb[4];
  float4 Ra0, Ra1;
  {
#pragma unroll
    for (int i = 0; i < 4; ++i)
      Rb[i] = *(const s16x8*)(gb + i * 4096);
    const float4* ap = (const float4*)(x + (size_t)arow * DIMK + g * 8);
    Ra0 = ap[0]; Ra1 = ap[1];
  }

  f32x4 acc[16];
#pragma unroll
  for (int j = 0; j < 16; ++j) acc[j] = (f32x4){0.f, 0.f, 0.f, 0.f};

  int cur = 0;
  for (int t = 0; t < 16; ++t) {
    // stage B-tile for step t
#pragma unroll
    for (int i = 0; i < 4; ++i)
      *(s16x8*)(lds + cur * 16384 + i * 4096 + tid * 16) = Rb[i];
    __syncthreads();

    // prefetch next step (redundant reload of t=15 at the end; harmless)
    const int tn = (t + 1 < 16) ? (t + 1) : 15;
    s16x8 nRb[4];
#pragma unroll
    for (int i = 0; i < 4; ++i)
      nRb[i] = *(const s16x8*)(gb + tn * 16384 + i * 4096);
    const float4* ap = (const float4*)(x + (size_t)arow * DIMK + tn * 32 + g * 8);
    float4 na0 = ap[0], na1 = ap[1];

    // A fragment for step t (f32 -> bf16)
    s16x8 af;
    af[0] = (short)f2bf(Ra0.x); af[1] = (short)f2bf(Ra0.y);
    af[2] = (short)f2bf(Ra0.z); af[3] = (short)f2bf(Ra0.w);
    af[4] = (short)f2bf(Ra1.x); af[5] = (short)f2bf(Ra1.y);
    af[6] = (short)f2bf(Ra1.z); af[7] = (short)f2bf(Ra1.w);

#pragma unroll
    for (int j = 0; j < 16; ++j) {
      const int c = j * 16 + r;
      const s16x8 bf = *(const s16x8*)(lds + cur * 16384 + c * 64 +
                                       ((g ^ ((c >> 1) & 3)) << 4));
      acc[j] = __builtin_amdgcn_mfma_f32_16x16x32_bf16(af, bf, acc[j], 0, 0, 0);
    }

#pragma unroll
    for (int i = 0; i < 4; ++i) Rb[i] = nRb[i];
    Ra0 = na0; Ra1 = na1;
    cur ^= 1;
  }

  // epilogue: D row = 4*(lane>>4)+reg, col = j*16 + (lane&15)
  int orow[4]; float dsv[4];
#pragma unroll
  for (int rr = 0; rr < 4; ++rr) {
    orow[rr] = rowbase + 4 * g + rr;
    dsv[rr] = (orow[rr] < NN) ? dis[orow[rr]] : 0.f;
  }
#pragma unroll
  for (int j = 0; j < 16; ++j) {
#pragma unroll
    for (int rr = 0; rr < 4; ++rr) {
      if (orow[rr] < NN)
        h1s[(size_t)orow[rr] * HIDN + j * 16 + r] = f2bf(acc[j][rr] * dsv[rr]);
    }
  }
}

// ---------------- fused: aggregate h1s (CSR) + b1 + ReLU + @W2 -> h2s (pre-scaled) ----------------
__global__ __launch_bounds__(256) void k_agg1(const unsigned short* __restrict__ h1s,
                                              const int* __restrict__ offsets,
                                              const int* __restrict__ ssorted,
                                              const float* __restrict__ dis,
                                              const float* __restrict__ b1,
                                              const float* __restrict__ W2,
                                              float* __restrict__ h2s) {
  const int w = threadIdx.x >> 6;
  const int l = threadIdx.x & 63;
  const int d = blockIdx.x * 4 + w;
  if (d >= NN) return;

  float a0, a1, a2, a3;
  {                                    // self term
    uint2 v = *(const uint2*)(h1s + (size_t)d * HIDN + l * 4);
    a0 = __uint_as_float(v.x << 16);
    a1 = __uint_as_float(v.x & 0xffff0000u);
    a2 = __uint_as_float(v.y << 16);
    a3 = __uint_as_float(v.y & 0xffff0000u);
  }
  const int off0 = offsets[d], off1 = offsets[d + 1];
  int e = off0;
  for (; e + 4 <= off1; e += 4) {
    int s0 = ssorted[e], s1 = ssorted[e + 1], s2 = ssorted[e + 2], s3 = ssorted[e + 3];
    uint2 v0 = *(const uint2*)(h1s + (size_t)s0 * HIDN + l * 4);
    uint2 v1 = *(const uint2*)(h1s + (size_t)s1 * HIDN + l * 4);
    uint2 v2 = *(const uint2*)(h1s + (size_t)s2 * HIDN + l * 4);
    uint2 v3 = *(const uint2*)(h1s + (size_t)s3 * HIDN + l * 4);
    a0 += __uint_as_float(v0.x << 16) + __uint_as_float(v1.x << 16) +
          __uint_as_float(v2.x << 16) + __uint_as_float(v3.x << 16);
    a1 += __uint_as_float(v0.x & 0xffff0000u) + __uint_as_float(v1.x & 0xffff0000u) +
          __uint_as_float(v2.x & 0xffff0000u) + __uint_as_float(v3.x & 0xffff0000u);
    a2 += __uint_as_float(v0.y << 16) + __uint_as_float(v1.y << 16) +
          __uint_as_float(v2.y << 16) + __uint_as_float(v3.y << 16);
    a3 += __uint_as_float(v0.y & 0xffff0000u) + __uint_as_float(v1.y & 0xffff0000u) +
          __uint_as_float(v2.y & 0xffff0000u) + __uint_as_float(v3.y & 0xffff0000u);
  }
  for (; e < off1; ++e) {
    int s = ssorted[e];
    uint2 v = *(const uint2*)(h1s + (size_t)s * HIDN + l * 4);
    a0 += __uint_as_float(v.x << 16);
    a1 += __uint_as_float(v.x & 0xffff0000u);
    a2 += __uint_as_float(v.y << 16);
    a3 += __uint_as_float(v.y & 0xffff0000u);
  }

  const float dsd = dis[d];
  const int c0 = l * 4;
  float r0 = fmaxf(a0 * dsd + b1[c0 + 0], 0.f);
  float r1 = fmaxf(a1 * dsd + b1[c0 + 1], 0.f);
  float r2 = fmaxf(a2 * dsd + b1[c0 + 2], 0.f);
  float r3 = fmaxf(a3 * dsd + b1[c0 + 3], 0.f);

  float p0 = r0 * W2[(c0 + 0) * 2] + r1 * W2[(c0 + 1) * 2] +
             r2 * W2[(c0 + 2) * 2] + r3 * W2[(c0 + 3) * 2];
  float p1 = r0 * W2[(c0 + 0) * 2 + 1] + r1 * W2[(c0 + 1) * 2 + 1] +
             r2 * W2[(c0 + 2) * 2 + 1] + r3 * W2[(c0 + 3) * 2 + 1];
#pragma unroll
  for (int o = 1; o < 64; o <<= 1) {
    p0 += __shfl_xor(p0, o);
    p1 += __shfl_xor(p1, o);
  }
  if (l == 0) {
    h2s[(size_t)d * 2 + 0] = dsd * p0;   // pre-scaled by dis[d] for layer-2 gather
    h2s[(size_t)d * 2 + 1] = dsd * p1;
  }
}

// ---------------- layer-2 aggregation (2 cols) ----------------
__global__ void k_agg2(const float* __restrict__ h2s, const int* __restrict__ offsets,
                       const int* __restrict__ ssorted, const float* __restrict__ dis,
                       const float* __restrict__ b2, float* __restrict__ out) {
  int d = blockIdx.x * 256 + threadIdx.x;
  if (d >= NN) return;
  float2 sv = *(const float2*)(h2s + (size_t)d * 2);
  float a0 = sv.x, a1 = sv.y;
  int off0 = offsets[d], off1 = offsets[d + 1];
  int e = off0;
  for (; e + 4 <= off1; e += 4) {
    int s0 = ssorted[e], s1 = ssorted[e + 1], s2 = ssorted[e + 2], s3 = ssorted[e + 3];
    float2 v0 = *(const float2*)(h2s + (size_t)s0 * 2);
    float2 v1 = *(const float2*)(h2s + (size_t)s1 * 2);
    float2 v2 = *(const float2*)(h2s + (size_t)s2 * 2);
    float2 v3 = *(const float2*)(h2s + (size_t)s3 * 2);
    a0 += v0.x + v1.x + v2.x + v3.x;
    a1 += v0.y + v1.y + v2.y + v3.y;
  }
  for (; e < off1; ++e) {
    int s = ssorted[e];
    float2 v = *(const float2*)(h2s + (size_t)s * 2);
    a0 += v.x; a1 += v.y;
  }
  float dsd = dis[d];
  out[(size_t)d * 2 + 0] = dsd * a0 + b2[0];
  out[(size_t)d * 2 + 1] = dsd * a1 + b2[1];
}

extern "C" void kernel_launch(void* const* d_in, const int* in_sizes, int n_in,
                              void* d_out, int out_size, void* d_ws, size_t ws_size,
                              hipStream_t stream) {
  (void)in_sizes; (void)n_in; (void)out_size; (void)ws_size;
  const float* x   = (const float*)d_in[0];
  const float* W1  = (const float*)d_in[1];
  const float* b1  = (const float*)d_in[2];
  const float* W2  = (const float*)d_in[3];
  const float* b2  = (const float*)d_in[4];
  const int*   ei  = (const int*)d_in[5];
  const int* esrc = ei;
  const int* edst = ei + NE;
  float* out = (float*)d_out;

  char* ws = (char*)d_ws;
  // workspace layout (all 16B-aligned), total ~30.3 MB
  unsigned short* h1s = (unsigned short*)(ws + 0);          // 25,600,000 B
  char*  w1t     = ws + 25600000;                           //    262,144 B
  float* dis     = (float*)(ws + 25862144);                 //    200,000 B
  float* h2s     = (float*)(ws + 26062144);                 //    400,000 B
  int*   cnt     = (int*)(ws + 26462144);                   //    200,000 B
  int*   offsets = (int*)(ws + 26662144);                   //    200,004 B
  int*   cursor  = (int*)(ws + 26862208);                   //    200,000 B
  int*   ssorted = (int*)(ws + 27062208);                   //  3,200,000 B

  hipMemsetAsync(cnt, 0, NN * sizeof(int), stream);
  k_hist<<<(NE + 255) / 256, 256, 0, stream>>>(edst, cnt);
  k_scan<<<1, 1024, 0, stream>>>(cnt, offsets, cursor, dis);
  k_scatter<<<(NE + 255) / 256, 256, 0, stream>>>(esrc, edst, cursor, ssorted);
  k_prep_w1t<<<(DIMK * HIDN) / 256, 256, 0, stream>>>(W1, w1t);
  k_gemm1<<<(NN + 63) / 64, 256, 0, stream>>>(x, w1t, dis, h1s);
  k_agg1<<<(NN + 3) / 4, 256, 0, stream>>>(h1s, offsets, ssorted, dis, b1, W2, h2s);
  k_agg2<<<(NN + 255) / 256, 256, 0, stream>>>(h2s, offsets, ssorted, dis, b2, out);
}

// Round 2
// 222.135 us; speedup vs baseline: 1.5782x; 1.5782x over previous
//
#include <hip/hip_runtime.h>
#include <stdint.h>

#define NN   50000
#define DIMK 512
#define HIDN 256
#define NE   800000

#define SCAN_ITEMS 4
#define SCAN_BLK 256
#define SCAN_PER_BLOCK (SCAN_ITEMS * SCAN_BLK)              // 1024
#define NBLK ((NN + SCAN_PER_BLOCK - 1) / SCAN_PER_BLOCK)   // 49

typedef float f32x4 __attribute__((ext_vector_type(4)));
typedef short s16x8 __attribute__((ext_vector_type(8)));

static __device__ __forceinline__ unsigned short f2bf(float f) {
  union { float f; uint32_t u; } v; v.f = f;
  uint32_t u = v.u;
  u += 0x7fffu + ((u >> 16) & 1u);   // RNE
  return (unsigned short)(u >> 16);
}

// ---------------- degree histogram ----------------
__global__ void k_hist(const int* __restrict__ edst, int* __restrict__ cnt) {
  int e = blockIdx.x * 256 + threadIdx.x;
  if (e < NE) atomicAdd(&cnt[edst[e]], 1);
}

// ---------------- device-wide scan, stage 1: per-block sums ----------------
__global__ __launch_bounds__(256) void k_blocksum(const int* __restrict__ cnt,
                                                  int* __restrict__ blocksum) {
  const int t = threadIdx.x;
  const int base = blockIdx.x * SCAN_PER_BLOCK + t * SCAN_ITEMS;
  int s = 0;
#pragma unroll
  for (int j = 0; j < SCAN_ITEMS; ++j) { int i = base + j; if (i < NN) s += cnt[i]; }
#pragma unroll
  for (int o = 1; o < 64; o <<= 1) s += __shfl_xor(s, o);
  __shared__ int wsum[4];
  if ((t & 63) == 0) wsum[t >> 6] = s;
  __syncthreads();
  if (t == 0) blocksum[blockIdx.x] = wsum[0] + wsum[1] + wsum[2] + wsum[3];
}

// ---------------- stage 2: scan the 49 block sums (one wave) ----------------
__global__ void k_scanblocks(const int* __restrict__ blocksum, int* __restrict__ blockoff) {
  const int t = threadIdx.x;   // 64 threads
  int own = (t < NBLK) ? blocksum[t] : 0;
  int v = own;
#pragma unroll
  for (int o = 1; o < 64; o <<= 1) { int u = __shfl_up(v, o); if (t >= o) v += u; }
  if (t < NBLK) blockoff[t] = v - own;   // exclusive
}

// ---------------- stage 3: local scan + write offsets/cursor/dis ----------------
__global__ __launch_bounds__(256) void k_finalize(const int* __restrict__ cnt,
                                                  const int* __restrict__ blockoff,
                                                  int* __restrict__ offsets,
                                                  int* __restrict__ cursor,
                                                  float* __restrict__ dis) {
  const int t = threadIdx.x;
  const int l = t & 63, w = t >> 6;
  const int base = blockIdx.x * SCAN_PER_BLOCK + t * SCAN_ITEMS;
  int c[SCAN_ITEMS]; int s = 0;
#pragma unroll
  for (int j = 0; j < SCAN_ITEMS; ++j) { int i = base + j; c[j] = (i < NN) ? cnt[i] : 0; s += c[j]; }
  const int own = s;
#pragma unroll
  for (int o = 1; o < 64; o <<= 1) { int u = __shfl_up(s, o); if (l >= o) s += u; }
  __shared__ int wt[4];
  if (l == 63) wt[w] = s;
  __syncthreads();
  int waveoff = 0;
  for (int ww = 0; ww < w; ++ww) waveoff += wt[ww];
  int run = blockoff[blockIdx.x] + waveoff + (s - own);   // exclusive prefix
#pragma unroll
  for (int j = 0; j < SCAN_ITEMS; ++j) {
    int i = base + j;
    if (i < NN) {
      offsets[i] = run;
      cursor[i]  = run;
      dis[i] = rsqrtf((float)(c[j] + 1));   // +1 self loop
      run += c[j];
    }
  }
  if (blockIdx.x == 0 && t == 0) offsets[NN] = NE;
}

// ---------------- CSR scatter ----------------
__global__ void k_scatter(const int* __restrict__ esrc, const int* __restrict__ edst,
                          int* __restrict__ cursor, int* __restrict__ ssorted) {
  int e = blockIdx.x * 256 + threadIdx.x;
  if (e < NE) {
    int d = edst[e];
    int p = atomicAdd(&cursor[d], 1);
    ssorted[p] = esrc[e];
  }
}

// ---------------- W1^T -> bf16, pre-swizzled per-kstep LDS image ----------------
// image for kstep t (16KB): element (k=32t+8g+i, col c) at byte
//   t*16384 + c*64 + ((g ^ ((c>>1)&3))<<4) + 2*i
__global__ void k_prep_w1t(const float* __restrict__ W1, char* __restrict__ w1t) {
  int tid = blockIdx.x * 256 + threadIdx.x;   // 512*256 = 131072 = DIMK*HIDN
  int c  = tid & 255;
  int k  = tid >> 8;
  int tt = k >> 5;
  int kk = k & 31;
  int g  = kk >> 3;
  int i  = kk & 7;
  unsigned short v = f2bf(W1[k * HIDN + c]);
  int byte = tt * 16384 + c * 64 + ((g ^ ((c >> 1) & 3)) << 4) + i * 2;
  *(unsigned short*)(w1t + byte) = v;
}

// ---------------- GEMM1: h1s = bf16(dis[row] * (x @ W1)) ----------------
// block: 4 waves, 64 rows x 256 cols; BK=32; dbuf LDS B-tile; A from global.
__global__ __launch_bounds__(256) void k_gemm1(const float* __restrict__ x,
                                               const char* __restrict__ w1t,
                                               const float* __restrict__ dis,
                                               unsigned short* __restrict__ h1s) {
  __shared__ char lds[32768];
  const int tid = threadIdx.x;
  const int l = tid & 63;
  const int r = l & 15;
  const int g = l >> 4;
  const int rowbase = blockIdx.x * 64 + (tid >> 6) * 16;
  int arow = rowbase + r;
  if (arow >= NN) arow = NN - 1;      // clamp; stores are guarded

  const char* gb = w1t + tid * 16;

  s16x8 Rb[4];
  float4 Ra0, Ra1;
  {
#pragma unroll
    for (int i = 0; i < 4; ++i)
      Rb[i] = *(const s16x8*)(gb + i * 4096);
    const float4* ap = (const float4*)(x + (size_t)arow * DIMK + g * 8);
    Ra0 = ap[0]; Ra1 = ap[1];
  }

  f32x4 acc[16];
#pragma unroll
  for (int j = 0; j < 16; ++j) acc[j] = (f32x4){0.f, 0.f, 0.f, 0.f};

  int cur = 0;
  for (int t = 0; t < 16; ++t) {
    // stage B-tile for step t
#pragma unroll
    for (int i = 0; i < 4; ++i)
      *(s16x8*)(lds + cur * 16384 + i * 4096 + tid * 16) = Rb[i];
    __syncthreads();

    // prefetch next step (redundant reload of t=15 at the end; harmless)
    const int tn = (t + 1 < 16) ? (t + 1) : 15;
    s16x8 nRb[4];
#pragma unroll
    for (int i = 0; i < 4; ++i)
      nRb[i] = *(const s16x8*)(gb + tn * 16384 + i * 4096);
    const float4* ap = (const float4*)(x + (size_t)arow * DIMK + tn * 32 + g * 8);
    float4 na0 = ap[0], na1 = ap[1];

    // A fragment for step t (f32 -> bf16)
    s16x8 af;
    af[0] = (short)f2bf(Ra0.x); af[1] = (short)f2bf(Ra0.y);
    af[2] = (short)f2bf(Ra0.z); af[3] = (short)f2bf(Ra0.w);
    af[4] = (short)f2bf(Ra1.x); af[5] = (short)f2bf(Ra1.y);
    af[6] = (short)f2bf(Ra1.z); af[7] = (short)f2bf(Ra1.w);

#pragma unroll
    for (int j = 0; j < 16; ++j) {
      const int c = j * 16 + r;
      const s16x8 bf = *(const s16x8*)(lds + cur * 16384 + c * 64 +
                                       ((g ^ ((c >> 1) & 3)) << 4));
      acc[j] = __builtin_amdgcn_mfma_f32_16x16x32_bf16(af, bf, acc[j], 0, 0, 0);
    }

#pragma unroll
    for (int i = 0; i < 4; ++i) Rb[i] = nRb[i];
    Ra0 = na0; Ra1 = na1;
    cur ^= 1;
  }

  // epilogue: D row = 4*(lane>>4)+reg, col = j*16 + (lane&15)
  int orow[4]; float dsv[4];
#pragma unroll
  for (int rr = 0; rr < 4; ++rr) {
    orow[rr] = rowbase + 4 * g + rr;
    dsv[rr] = (orow[rr] < NN) ? dis[orow[rr]] : 0.f;
  }
#pragma unroll
  for (int j = 0; j < 16; ++j) {
#pragma unroll
    for (int rr = 0; rr < 4; ++rr) {
      if (orow[rr] < NN)
        h1s[(size_t)orow[rr] * HIDN + j * 16 + r] = f2bf(acc[j][rr] * dsv[rr]);
    }
  }
}

// ---------------- fused: aggregate h1s (CSR) + b1 + ReLU + @W2 -> h2s (pre-scaled) ----------------
__global__ __launch_bounds__(256) void k_agg1(const unsigned short* __restrict__ h1s,
                                              const int* __restrict__ offsets,
                                              const int* __restrict__ ssorted,
                                              const float* __restrict__ dis,
                                              const float* __restrict__ b1,
                                              const float* __restrict__ W2,
                                              float* __restrict__ h2s) {
  const int w = threadIdx.x >> 6;
  const int l = threadIdx.x & 63;
  const int d = blockIdx.x * 4 + w;
  if (d >= NN) return;

  float a0, a1, a2, a3;
  {                                    // self term
    uint2 v = *(const uint2*)(h1s + (size_t)d * HIDN + l * 4);
    a0 = __uint_as_float(v.x << 16);
    a1 = __uint_as_float(v.x & 0xffff0000u);
    a2 = __uint_as_float(v.y << 16);
    a3 = __uint_as_float(v.y & 0xffff0000u);
  }
  const int off0 = offsets[d], off1 = offsets[d + 1];
  int e = off0;
  for (; e + 4 <= off1; e += 4) {
    int s0 = ssorted[e], s1 = ssorted[e + 1], s2 = ssorted[e + 2], s3 = ssorted[e + 3];
    uint2 v0 = *(const uint2*)(h1s + (size_t)s0 * HIDN + l * 4);
    uint2 v1 = *(const uint2*)(h1s + (size_t)s1 * HIDN + l * 4);
    uint2 v2 = *(const uint2*)(h1s + (size_t)s2 * HIDN + l * 4);
    uint2 v3 = *(const uint2*)(h1s + (size_t)s3 * HIDN + l * 4);
    a0 += __uint_as_float(v0.x << 16) + __uint_as_float(v1.x << 16) +
          __uint_as_float(v2.x << 16) + __uint_as_float(v3.x << 16);
    a1 += __uint_as_float(v0.x & 0xffff0000u) + __uint_as_float(v1.x & 0xffff0000u) +
          __uint_as_float(v2.x & 0xffff0000u) + __uint_as_float(v3.x & 0xffff0000u);
    a2 += __uint_as_float(v0.y << 16) + __uint_as_float(v1.y << 16) +
          __uint_as_float(v2.y << 16) + __uint_as_float(v3.y << 16);
    a3 += __uint_as_float(v0.y & 0xffff0000u) + __uint_as_float(v1.y & 0xffff0000u) +
          __uint_as_float(v2.y & 0xffff0000u) + __uint_as_float(v3.y & 0xffff0000u);
  }
  for (; e < off1; ++e) {
    int s = ssorted[e];
    uint2 v = *(const uint2*)(h1s + (size_t)s * HIDN + l * 4);
    a0 += __uint_as_float(v.x << 16);
    a1 += __uint_as_float(v.x & 0xffff0000u);
    a2 += __uint_as_float(v.y << 16);
    a3 += __uint_as_float(v.y & 0xffff0000u);
  }

  const float dsd = dis[d];
  const int c0 = l * 4;
  float r0 = fmaxf(a0 * dsd + b1[c0 + 0], 0.f);
  float r1 = fmaxf(a1 * dsd + b1[c0 + 1], 0.f);
  float r2 = fmaxf(a2 * dsd + b1[c0 + 2], 0.f);
  float r3 = fmaxf(a3 * dsd + b1[c0 + 3], 0.f);

  float p0 = r0 * W2[(c0 + 0) * 2] + r1 * W2[(c0 + 1) * 2] +
             r2 * W2[(c0 + 2) * 2] + r3 * W2[(c0 + 3) * 2];
  float p1 = r0 * W2[(c0 + 0) * 2 + 1] + r1 * W2[(c0 + 1) * 2 + 1] +
             r2 * W2[(c0 + 2) * 2 + 1] + r3 * W2[(c0 + 3) * 2 + 1];
#pragma unroll
  for (int o = 1; o < 64; o <<= 1) {
    p0 += __shfl_xor(p0, o);
    p1 += __shfl_xor(p1, o);
  }
  if (l == 0) {
    h2s[(size_t)d * 2 + 0] = dsd * p0;   // pre-scaled by dis[d] for layer-2 gather
    h2s[(size_t)d * 2 + 1] = dsd * p1;
  }
}

// ---------------- layer-2 aggregation (2 cols) ----------------
__global__ void k_agg2(const float* __restrict__ h2s, const int* __restrict__ offsets,
                       const int* __restrict__ ssorted, const float* __restrict__ dis,
                       const float* __restrict__ b2, float* __restrict__ out) {
  int d = blockIdx.x * 256 + threadIdx.x;
  if (d >= NN) return;
  float2 sv = *(const float2*)(h2s + (size_t)d * 2);
  float a0 = sv.x, a1 = sv.y;
  int off0 = offsets[d], off1 = offsets[d + 1];
  int e = off0;
  for (; e + 4 <= off1; e += 4) {
    int s0 = ssorted[e], s1 = ssorted[e + 1], s2 = ssorted[e + 2], s3 = ssorted[e + 3];
    float2 v0 = *(const float2*)(h2s + (size_t)s0 * 2);
    float2 v1 = *(const float2*)(h2s + (size_t)s1 * 2);
    float2 v2 = *(const float2*)(h2s + (size_t)s2 * 2);
    float2 v3 = *(const float2*)(h2s + (size_t)s3 * 2);
    a0 += v0.x + v1.x + v2.x + v3.x;
    a1 += v0.y + v1.y + v2.y + v3.y;
  }
  for (; e < off1; ++e) {
    int s = ssorted[e];
    float2 v = *(const float2*)(h2s + (size_t)s * 2);
    a0 += v.x; a1 += v.y;
  }
  float dsd = dis[d];
  out[(size_t)d * 2 + 0] = dsd * a0 + b2[0];
  out[(size_t)d * 2 + 1] = dsd * a1 + b2[1];
}

extern "C" void kernel_launch(void* const* d_in, const int* in_sizes, int n_in,
                              void* d_out, int out_size, void* d_ws, size_t ws_size,
                              hipStream_t stream) {
  (void)in_sizes; (void)n_in; (void)out_size; (void)ws_size;
  const float* x   = (const float*)d_in[0];
  const float* W1  = (const float*)d_in[1];
  const float* b1  = (const float*)d_in[2];
  const float* W2  = (const float*)d_in[3];
  const float* b2  = (const float*)d_in[4];
  const int*   ei  = (const int*)d_in[5];
  const int* esrc = ei;
  const int* edst = ei + NE;
  float* out = (float*)d_out;

  char* ws = (char*)d_ws;
  // workspace layout (all 16B-aligned), total ~30.3 MB
  unsigned short* h1s = (unsigned short*)(ws + 0);          // 25,600,000 B
  char*  w1t     = ws + 25600000;                           //    262,144 B
  float* dis     = (float*)(ws + 25862144);                 //    200,000 B
  float* h2s     = (float*)(ws + 26062144);                 //    400,000 B
  int*   cnt     = (int*)(ws + 26462144);                   //    200,000 B
  int*   offsets = (int*)(ws + 26662144);                   //    200,004 B
  int*   cursor  = (int*)(ws + 26862208);                   //    200,000 B
  int*   ssorted = (int*)(ws + 27062208);                   //  3,200,000 B
  int*   blocksum= (int*)(ws + 30262208);                   //        196 B
  int*   blockoff= (int*)(ws + 30262464);                   //        196 B

  hipMemsetAsync(cnt, 0, NN * sizeof(int), stream);
  k_hist<<<(NE + 255) / 256, 256, 0, stream>>>(edst, cnt);
  k_blocksum<<<NBLK, 256, 0, stream>>>(cnt, blocksum);
  k_scanblocks<<<1, 64, 0, stream>>>(blocksum, blockoff);
  k_finalize<<<NBLK, 256, 0, stream>>>(cnt, blockoff, offsets, cursor, dis);
  k_scatter<<<(NE + 255) / 256, 256, 0, stream>>>(esrc, edst, cursor, ssorted);
  k_prep_w1t<<<(DIMK * HIDN) / 256, 256, 0, stream>>>(W1, w1t);
  k_gemm1<<<(NN + 63) / 64, 256, 0, stream>>>(x, w1t, dis, h1s);
  k_agg1<<<(NN + 3) / 4, 256, 0, stream>>>(h1s, offsets, ssorted, dis, b1, W2, h2s);
  k_agg2<<<(NN + 255) / 256, 256, 0, stream>>>(h2s, offsets, ssorted, dis, b2, out);
}

// Round 3
// 220.563 us; speedup vs baseline: 1.5895x; 1.0071x over previous
//
#include <hip/hip_runtime.h>
#include <stdint.h>

#define NN   50000
#define DIMK 512
#define HIDN 256
#define NE   800000

#define SCAN_ITEMS 4
#define SCAN_BLK 256
#define SCAN_PER_BLOCK (SCAN_ITEMS * SCAN_BLK)              // 1024
#define NBLK ((NN + SCAN_PER_BLOCK - 1) / SCAN_PER_BLOCK)   // 49

typedef float f32x4  __attribute__((ext_vector_type(4)));
typedef float f32x16 __attribute__((ext_vector_type(16)));
typedef short s16x8  __attribute__((ext_vector_type(8)));

static __device__ __forceinline__ unsigned short f2bf(float f) {
  union { float f; uint32_t u; } v; v.f = f;
  uint32_t u = v.u;
  u += 0x7fffu + ((u >> 16) & 1u);   // RNE
  return (unsigned short)(u >> 16);
}

static __device__ __forceinline__ uint32_t cvt_pk_bf16(float lo, float hi) {
  uint32_t r;
  asm("v_cvt_pk_bf16_f32 %0, %1, %2" : "=v"(r) : "v"(lo), "v"(hi));
  return r;   // low16 = bf16(lo), high16 = bf16(hi), RNE
}

// ---------------- degree histogram ----------------
__global__ void k_hist(const int* __restrict__ edst, int* __restrict__ cnt) {
  int e = blockIdx.x * 256 + threadIdx.x;
  if (e < NE) atomicAdd(&cnt[edst[e]], 1);
}

// ---------------- device-wide scan, stage 1: per-block sums ----------------
__global__ __launch_bounds__(256) void k_blocksum(const int* __restrict__ cnt,
                                                  int* __restrict__ blocksum) {
  const int t = threadIdx.x;
  const int base = blockIdx.x * SCAN_PER_BLOCK + t * SCAN_ITEMS;
  int s = 0;
#pragma unroll
  for (int j = 0; j < SCAN_ITEMS; ++j) { int i = base + j; if (i < NN) s += cnt[i]; }
#pragma unroll
  for (int o = 1; o < 64; o <<= 1) s += __shfl_xor(s, o);
  __shared__ int wsum[4];
  if ((t & 63) == 0) wsum[t >> 6] = s;
  __syncthreads();
  if (t == 0) blocksum[blockIdx.x] = wsum[0] + wsum[1] + wsum[2] + wsum[3];
}

// ---------------- stage 2: scan the 49 block sums (one wave) ----------------
__global__ void k_scanblocks(const int* __restrict__ blocksum, int* __restrict__ blockoff) {
  const int t = threadIdx.x;   // 64 threads
  int own = (t < NBLK) ? blocksum[t] : 0;
  int v = own;
#pragma unroll
  for (int o = 1; o < 64; o <<= 1) { int u = __shfl_up(v, o); if (t >= o) v += u; }
  if (t < NBLK) blockoff[t] = v - own;   // exclusive
}

// ---------------- stage 3: local scan + write offsets/cursor/dis ----------------
__global__ __launch_bounds__(256) void k_finalize(const int* __restrict__ cnt,
                                                  const int* __restrict__ blockoff,
                                                  int* __restrict__ offsets,
                                                  int* __restrict__ cursor,
                                                  float* __restrict__ dis) {
  const int t = threadIdx.x;
  const int l = t & 63, w = t >> 6;
  const int base = blockIdx.x * SCAN_PER_BLOCK + t * SCAN_ITEMS;
  int c[SCAN_ITEMS]; int s = 0;
#pragma unroll
  for (int j = 0; j < SCAN_ITEMS; ++j) { int i = base + j; c[j] = (i < NN) ? cnt[i] : 0; s += c[j]; }
  const int own = s;
#pragma unroll
  for (int o = 1; o < 64; o <<= 1) { int u = __shfl_up(s, o); if (l >= o) s += u; }
  __shared__ int wt[4];
  if (l == 63) wt[w] = s;
  __syncthreads();
  int waveoff = 0;
  for (int ww = 0; ww < w; ++ww) waveoff += wt[ww];
  int run = blockoff[blockIdx.x] + waveoff + (s - own);   // exclusive prefix
#pragma unroll
  for (int j = 0; j < SCAN_ITEMS; ++j) {
    int i = base + j;
    if (i < NN) {
      offsets[i] = run;
      cursor[i]  = run;
      dis[i] = rsqrtf((float)(c[j] + 1));   // +1 self loop
      run += c[j];
    }
  }
  if (blockIdx.x == 0 && t == 0) offsets[NN] = NE;
}

// ---------------- CSR scatter ----------------
__global__ void k_scatter(const int* __restrict__ esrc, const int* __restrict__ edst,
                          int* __restrict__ cursor, int* __restrict__ ssorted) {
  int e = blockIdx.x * 256 + threadIdx.x;
  if (e < NE) {
    int d = edst[e];
    int p = atomicAdd(&cursor[d], 1);
    ssorted[p] = esrc[e];
  }
}

// ---------------- W1^T -> bf16, fragment-contiguous image for 32x32x16 MFMA ----
// fragment (t, j): 1KB, lane l, elem i at byte (t*8+j)*1024 + l*16 + 2*i
// holds element k = t*16 + 8*(l>>5) + i, col = j*32 + (l&31)
__global__ void k_prep_w1t(const float* __restrict__ W1, char* __restrict__ w1t) {
  int tid = blockIdx.x * 256 + threadIdx.x;   // 512*256 = 131072 = DIMK*HIDN
  int c  = tid & 255;
  int k  = tid >> 8;
  int t  = k >> 4;
  int kk = k & 15;
  int g  = kk >> 3;
  int i  = kk & 7;
  int j  = c >> 5;
  int cc = c & 31;
  unsigned short v = f2bf(W1[k * HIDN + c]);
  *(unsigned short*)(w1t + (t * 8 + j) * 1024 + (g * 32 + cc) * 16 + i * 2) = v;
}

// ---------------- GEMM1: h1s = bf16(dis[row] * (x @ W1)) ----------------
// One independent wave per 32-row stripe, all 256 cols. No LDS, no barriers.
// mfma_f32_32x32x16_bf16; A prefetch 4 deep (HBM), B prefetch 2 deep (L2).
#define GSTEP(T, AC, BC)                                                        \
  {                                                                             \
    union { s16x8 v; uint32_t u[4]; } AF;                                       \
    AF.u[0] = cvt_pk_bf16(AC[0].x, AC[0].y);                                    \
    AF.u[1] = cvt_pk_bf16(AC[0].z, AC[0].w);                                    \
    AF.u[2] = cvt_pk_bf16(AC[1].x, AC[1].y);                                    \
    AF.u[3] = cvt_pk_bf16(AC[1].z, AC[1].w);                                    \
    _Pragma("unroll")                                                           \
    for (int j = 0; j < 8; ++j)                                                 \
      acc[j] = __builtin_amdgcn_mfma_f32_32x32x16_bf16(AF.v, BC[j], acc[j], 0, 0, 0); \
    if ((T) + 2 < 32) {                                                         \
      _Pragma("unroll")                                                         \
      for (int j = 0; j < 8; ++j)                                               \
        BC[j] = *(const s16x8*)(wb + ((T) + 2) * 8192 + j * 1024);              \
    }                                                                           \
    if ((T) + 4 < 32) {                                                         \
      AC[0] = ap[((T) + 4) * 4];                                                \
      AC[1] = ap[((T) + 4) * 4 + 1];                                            \
    }                                                                           \
  }

__global__ __launch_bounds__(256, 2) void k_gemm1(const float* __restrict__ x,
                                                  const char* __restrict__ w1t,
                                                  const float* __restrict__ dis,
                                                  unsigned short* __restrict__ h1s) {
  const int l = threadIdx.x & 63;
  const int wid = (blockIdx.x * 256 + threadIdx.x) >> 6;
  const int R0 = wid * 32;
  if (R0 >= NN) return;
  const int h = l >> 5;
  int ra = R0 + (l & 31);
  if (ra >= NN) ra = NN - 1;

  const float4* ap = (const float4*)(x + (size_t)ra * DIMK) + h * 2;
  const char* wb = w1t + l * 16;

  f32x16 acc[8];
#pragma unroll
  for (int j = 0; j < 8; ++j)
#pragma unroll
    for (int g = 0; g < 16; ++g) acc[j][g] = 0.f;

  // prologue: A steps 0..3, B steps 0..1
  float4 A0[2], A1[2], A2[2], A3[2];
  A0[0] = ap[0];  A0[1] = ap[1];
  A1[0] = ap[4];  A1[1] = ap[5];
  A2[0] = ap[8];  A2[1] = ap[9];
  A3[0] = ap[12]; A3[1] = ap[13];
  s16x8 Ba[8], Bb[8];
#pragma unroll
  for (int j = 0; j < 8; ++j) Ba[j] = *(const s16x8*)(wb + j * 1024);
#pragma unroll
  for (int j = 0; j < 8; ++j) Bb[j] = *(const s16x8*)(wb + 8192 + j * 1024);

#pragma unroll
  for (int q = 0; q < 8; ++q) {
    GSTEP(4 * q + 0, A0, Ba);
    GSTEP(4 * q + 1, A1, Bb);
    GSTEP(4 * q + 2, A2, Ba);
    GSTEP(4 * q + 3, A3, Bb);
  }

  // epilogue: D col = j*32 + (l&31), row = (reg&3) + 8*(reg>>2) + 4*(l>>5)
  const int cc = l & 31;
  float dv[16];
#pragma unroll
  for (int g = 0; g < 16; ++g) {
    int row = R0 + (g & 3) + 8 * (g >> 2) + 4 * h;
    dv[g] = (row < NN) ? dis[row] : 0.f;
  }
#pragma unroll
  for (int j = 0; j < 8; ++j) {
#pragma unroll
    for (int g = 0; g < 16; ++g) {
      int row = R0 + (g & 3) + 8 * (g >> 2) + 4 * h;
      if (row < NN)
        h1s[(size_t)row * HIDN + j * 32 + cc] = f2bf(acc[j][g] * dv[g]);
    }
  }
}

// ---------------- fused: aggregate h1s (CSR) + b1 + ReLU + @W2 -> h2s (pre-scaled) ----------------
__global__ __launch_bounds__(256) void k_agg1(const unsigned short* __restrict__ h1s,
                                              const int* __restrict__ offsets,
                                              const int* __restrict__ ssorted,
                                              const float* __restrict__ dis,
                                              const float* __restrict__ b1,
                                              const float* __restrict__ W2,
                                              float* __restrict__ h2s) {
  const int w = threadIdx.x >> 6;
  const int l = threadIdx.x & 63;
  const int d = blockIdx.x * 4 + w;
  if (d >= NN) return;

  float a0, a1, a2, a3;
  {                                    // self term
    uint2 v = *(const uint2*)(h1s + (size_t)d * HIDN + l * 4);
    a0 = __uint_as_float(v.x << 16);
    a1 = __uint_as_float(v.x & 0xffff0000u);
    a2 = __uint_as_float(v.y << 16);
    a3 = __uint_as_float(v.y & 0xffff0000u);
  }
  const int off0 = offsets[d], off1 = offsets[d + 1];
  int e = off0;
  for (; e + 4 <= off1; e += 4) {
    int s0 = ssorted[e], s1 = ssorted[e + 1], s2 = ssorted[e + 2], s3 = ssorted[e + 3];
    uint2 v0 = *(const uint2*)(h1s + (size_t)s0 * HIDN + l * 4);
    uint2 v1 = *(const uint2*)(h1s + (size_t)s1 * HIDN + l * 4);
    uint2 v2 = *(const uint2*)(h1s + (size_t)s2 * HIDN + l * 4);
    uint2 v3 = *(const uint2*)(h1s + (size_t)s3 * HIDN + l * 4);
    a0 += __uint_as_float(v0.x << 16) + __uint_as_float(v1.x << 16) +
          __uint_as_float(v2.x << 16) + __uint_as_float(v3.x << 16);
    a1 += __uint_as_float(v0.x & 0xffff0000u) + __uint_as_float(v1.x & 0xffff0000u) +
          __uint_as_float(v2.x & 0xffff0000u) + __uint_as_float(v3.x & 0xffff0000u);
    a2 += __uint_as_float(v0.y << 16) + __uint_as_float(v1.y << 16) +
          __uint_as_float(v2.y << 16) + __uint_as_float(v3.y << 16);
    a3 += __uint_as_float(v0.y & 0xffff0000u) + __uint_as_float(v1.y & 0xffff0000u) +
          __uint_as_float(v2.y & 0xffff0000u) + __uint_as_float(v3.y & 0xffff0000u);
  }
  for (; e < off1; ++e) {
    int s = ssorted[e];
    uint2 v = *(const uint2*)(h1s + (size_t)s * HIDN + l * 4);
    a0 += __uint_as_float(v.x << 16);
    a1 += __uint_as_float(v.x & 0xffff0000u);
    a2 += __uint_as_float(v.y << 16);
    a3 += __uint_as_float(v.y & 0xffff0000u);
  }

  const float dsd = dis[d];
  const int c0 = l * 4;
  float r0 = fmaxf(a0 * dsd + b1[c0 + 0], 0.f);
  float r1 = fmaxf(a1 * dsd + b1[c0 + 1], 0.f);
  float r2 = fmaxf(a2 * dsd + b1[c0 + 2], 0.f);
  float r3 = fmaxf(a3 * dsd + b1[c0 + 3], 0.f);

  float p0 = r0 * W2[(c0 + 0) * 2] + r1 * W2[(c0 + 1) * 2] +
             r2 * W2[(c0 + 2) * 2] + r3 * W2[(c0 + 3) * 2];
  float p1 = r0 * W2[(c0 + 0) * 2 + 1] + r1 * W2[(c0 + 1) * 2 + 1] +
             r2 * W2[(c0 + 2) * 2 + 1] + r3 * W2[(c0 + 3) * 2 + 1];
#pragma unroll
  for (int o = 1; o < 64; o <<= 1) {
    p0 += __shfl_xor(p0, o);
    p1 += __shfl_xor(p1, o);
  }
  if (l == 0) {
    h2s[(size_t)d * 2 + 0] = dsd * p0;   // pre-scaled by dis[d] for layer-2 gather
    h2s[(size_t)d * 2 + 1] = dsd * p1;
  }
}

// ---------------- layer-2 aggregation (2 cols) ----------------
__global__ void k_agg2(const float* __restrict__ h2s, const int* __restrict__ offsets,
                       const int* __restrict__ ssorted, const float* __restrict__ dis,
                       const float* __restrict__ b2, float* __restrict__ out) {
  int d = blockIdx.x * 256 + threadIdx.x;
  if (d >= NN) return;
  float2 sv = *(const float2*)(h2s + (size_t)d * 2);
  float a0 = sv.x, a1 = sv.y;
  int off0 = offsets[d], off1 = offsets[d + 1];
  int e = off0;
  for (; e + 4 <= off1; e += 4) {
    int s0 = ssorted[e], s1 = ssorted[e + 1], s2 = ssorted[e + 2], s3 = ssorted[e + 3];
    float2 v0 = *(const float2*)(h2s + (size_t)s0 * 2);
    float2 v1 = *(const float2*)(h2s + (size_t)s1 * 2);
    float2 v2 = *(const float2*)(h2s + (size_t)s2 * 2);
    float2 v3 = *(const float2*)(h2s + (size_t)s3 * 2);
    a0 += v0.x + v1.x + v2.x + v3.x;
    a1 += v0.y + v1.y + v2.y + v3.y;
  }
  for (; e < off1; ++e) {
    int s = ssorted[e];
    float2 v = *(const float2*)(h2s + (size_t)s * 2);
    a0 += v.x; a1 += v.y;
  }
  float dsd = dis[d];
  out[(size_t)d * 2 + 0] = dsd * a0 + b2[0];
  out[(size_t)d * 2 + 1] = dsd * a1 + b2[1];
}

extern "C" void kernel_launch(void* const* d_in, const int* in_sizes, int n_in,
                              void* d_out, int out_size, void* d_ws, size_t ws_size,
                              hipStream_t stream) {
  (void)in_sizes; (void)n_in; (void)out_size; (void)ws_size;
  const float* x   = (const float*)d_in[0];
  const float* W1  = (const float*)d_in[1];
  const float* b1  = (const float*)d_in[2];
  const float* W2  = (const float*)d_in[3];
  const float* b2  = (const float*)d_in[4];
  const int*   ei  = (const int*)d_in[5];
  const int* esrc = ei;
  const int* edst = ei + NE;
  float* out = (float*)d_out;

  char* ws = (char*)d_ws;
  // workspace layout (all 16B-aligned), total ~30.3 MB
  unsigned short* h1s = (unsigned short*)(ws + 0);          // 25,600,000 B
  char*  w1t     = ws + 25600000;                           //    262,144 B
  float* dis     = (float*)(ws + 25862144);                 //    200,000 B
  float* h2s     = (float*)(ws + 26062144);                 //    400,000 B
  int*   cnt     = (int*)(ws + 26462144);                   //    200,000 B
  int*   offsets = (int*)(ws + 26662144);                   //    200,004 B
  int*   cursor  = (int*)(ws + 26862208);                   //    200,000 B
  int*   ssorted = (int*)(ws + 27062208);                   //  3,200,000 B
  int*   blocksum= (int*)(ws + 30262208);                   //        196 B
  int*   blockoff= (int*)(ws + 30262464);                   //        196 B

  hipMemsetAsync(cnt, 0, NN * sizeof(int), stream);
  k_hist<<<(NE + 255) / 256, 256, 0, stream>>>(edst, cnt);
  k_blocksum<<<NBLK, 256, 0, stream>>>(cnt, blocksum);
  k_scanblocks<<<1, 64, 0, stream>>>(blocksum, blockoff);
  k_finalize<<<NBLK, 256, 0, stream>>>(cnt, blockoff, offsets, cursor, dis);
  k_scatter<<<(NE + 255) / 256, 256, 0, stream>>>(esrc, edst, cursor, ssorted);
  k_prep_w1t<<<(DIMK * HIDN) / 256, 256, 0, stream>>>(W1, w1t);
  {
    const int nwaves = (NN + 31) / 32;              // 1563
    const int nblk   = (nwaves + 3) / 4;            // 391
    k_gemm1<<<nblk, 256, 0, stream>>>(x, w1t, dis, h1s);
  }
  k_agg1<<<(NN + 3) / 4, 256, 0, stream>>>(h1s, offsets, ssorted, dis, b1, W2, h2s);
  k_agg2<<<(NN + 255) / 256, 256, 0, stream>>>(h2s, offsets, ssorted, dis, b2, out);
}

// Round 4
// 214.815 us; speedup vs baseline: 1.6320x; 1.0268x over previous
//
#include <hip/hip_runtime.h>
#include <stdint.h>

#define NN   50000
#define DIMK 512
#define HIDN 256
#define NE   800000

#define SCAN_ITEMS 4
#define SCAN_BLK 256
#define SCAN_PER_BLOCK (SCAN_ITEMS * SCAN_BLK)              // 1024
#define NBLK ((NN + SCAN_PER_BLOCK - 1) / SCAN_PER_BLOCK)   // 49

typedef float f32x4  __attribute__((ext_vector_type(4)));
typedef float f32x16 __attribute__((ext_vector_type(16)));
typedef short s16x8  __attribute__((ext_vector_type(8)));

static __device__ __forceinline__ unsigned short f2bf(float f) {
  union { float f; uint32_t u; } v; v.f = f;
  uint32_t u = v.u;
  u += 0x7fffu + ((u >> 16) & 1u);   // RNE
  return (unsigned short)(u >> 16);
}

static __device__ __forceinline__ uint32_t cvt_pk_bf16(float lo, float hi) {
  uint32_t r;
  asm("v_cvt_pk_bf16_f32 %0, %1, %2" : "=v"(r) : "v"(lo), "v"(hi));
  return r;   // low16 = bf16(lo), high16 = bf16(hi), RNE
}

// ---------------- degree histogram ----------------
__global__ void k_hist(const int* __restrict__ edst, int* __restrict__ cnt) {
  int e = blockIdx.x * 256 + threadIdx.x;
  if (e < NE) atomicAdd(&cnt[edst[e]], 1);
}

// ---------------- device-wide scan, stage 1: per-block sums ----------------
__global__ __launch_bounds__(256) void k_blocksum(const int* __restrict__ cnt,
                                                  int* __restrict__ blocksum) {
  const int t = threadIdx.x;
  const int base = blockIdx.x * SCAN_PER_BLOCK + t * SCAN_ITEMS;
  int s = 0;
#pragma unroll
  for (int j = 0; j < SCAN_ITEMS; ++j) { int i = base + j; if (i < NN) s += cnt[i]; }
#pragma unroll
  for (int o = 1; o < 64; o <<= 1) s += __shfl_xor(s, o);
  __shared__ int wsum[4];
  if ((t & 63) == 0) wsum[t >> 6] = s;
  __syncthreads();
  if (t == 0) blocksum[blockIdx.x] = wsum[0] + wsum[1] + wsum[2] + wsum[3];
}

// ---------------- stage 2: scan the 49 block sums (one wave) ----------------
__global__ void k_scanblocks(const int* __restrict__ blocksum, int* __restrict__ blockoff) {
  const int t = threadIdx.x;   // 64 threads
  int own = (t < NBLK) ? blocksum[t] : 0;
  int v = own;
#pragma unroll
  for (int o = 1; o < 64; o <<= 1) { int u = __shfl_up(v, o); if (t >= o) v += u; }
  if (t < NBLK) blockoff[t] = v - own;   // exclusive
}

// ---------------- stage 3: local scan + write offsets/cursor/dis ----------------
__global__ __launch_bounds__(256) void k_finalize(const int* __restrict__ cnt,
                                                  const int* __restrict__ blockoff,
                                                  int* __restrict__ offsets,
                                                  int* __restrict__ cursor,
                                                  float* __restrict__ dis) {
  const int t = threadIdx.x;
  const int l = t & 63, w = t >> 6;
  const int base = blockIdx.x * SCAN_PER_BLOCK + t * SCAN_ITEMS;
  int c[SCAN_ITEMS]; int s = 0;
#pragma unroll
  for (int j = 0; j < SCAN_ITEMS; ++j) { int i = base + j; c[j] = (i < NN) ? cnt[i] : 0; s += c[j]; }
  const int own = s;
#pragma unroll
  for (int o = 1; o < 64; o <<= 1) { int u = __shfl_up(s, o); if (l >= o) s += u; }
  __shared__ int wt[4];
  if (l == 63) wt[w] = s;
  __syncthreads();
  int waveoff = 0;
  for (int ww = 0; ww < w; ++ww) waveoff += wt[ww];
  int run = blockoff[blockIdx.x] + waveoff + (s - own);   // exclusive prefix
#pragma unroll
  for (int j = 0; j < SCAN_ITEMS; ++j) {
    int i = base + j;
    if (i < NN) {
      offsets[i] = run;
      cursor[i]  = run;
      dis[i] = rsqrtf((float)(c[j] + 1));   // +1 self loop
      run += c[j];
    }
  }
  if (blockIdx.x == 0 && t == 0) offsets[NN] = NE;
}

// ---------------- CSR scatter ----------------
__global__ void k_scatter(const int* __restrict__ esrc, const int* __restrict__ edst,
                          int* __restrict__ cursor, int* __restrict__ ssorted) {
  int e = blockIdx.x * 256 + threadIdx.x;
  if (e < NE) {
    int d = edst[e];
    int p = atomicAdd(&cursor[d], 1);
    ssorted[p] = esrc[e];
  }
}

// ---------------- W1^T -> bf16, fragment-contiguous image for 32x32x16 MFMA ----
// fragment (t, j): 1KB, lane l, elem i at byte (t*8+j)*1024 + l*16 + 2*i
// holds element k = t*16 + 8*(l>>5) + i, col = j*32 + (l&31)
__global__ void k_prep_w1t(const float* __restrict__ W1, char* __restrict__ w1t) {
  int tid = blockIdx.x * 256 + threadIdx.x;   // 512*256 = 131072 = DIMK*HIDN
  int c  = tid & 255;
  int k  = tid >> 8;
  int t  = k >> 4;
  int kk = k & 15;
  int g  = kk >> 3;
  int i  = kk & 7;
  int j  = c >> 5;
  int cc = c & 31;
  unsigned short v = f2bf(W1[k * HIDN + c]);
  *(unsigned short*)(w1t + (t * 8 + j) * 1024 + (g * 32 + cc) * 16 + i * 2) = v;
}

// ---------------- GEMM1: h1s = bf16(dis[row] * (x @ W1)) ----------------
// One independent wave per (32-row stripe, 128-col half). No LDS, no barriers.
// mfma_f32_32x32x16_bf16; A prefetch 4 deep, B prefetch 2 deep; acc = 64 AGPR.
#define GSTEP(T, AC, BC)                                                        \
  {                                                                             \
    union { s16x8 v; uint32_t u[4]; } AF;                                       \
    AF.u[0] = cvt_pk_bf16(AC[0].x, AC[0].y);                                    \
    AF.u[1] = cvt_pk_bf16(AC[0].z, AC[0].w);                                    \
    AF.u[2] = cvt_pk_bf16(AC[1].x, AC[1].y);                                    \
    AF.u[3] = cvt_pk_bf16(AC[1].z, AC[1].w);                                    \
    _Pragma("unroll")                                                           \
    for (int j = 0; j < 4; ++j)                                                 \
      acc[j] = __builtin_amdgcn_mfma_f32_32x32x16_bf16(AF.v, BC[j], acc[j], 0, 0, 0); \
    if ((T) + 2 < 32) {                                                         \
      _Pragma("unroll")                                                         \
      for (int j = 0; j < 4; ++j)                                               \
        BC[j] = *(const s16x8*)(wb + ((T) + 2) * 8192 + j * 1024);              \
    }                                                                           \
    if ((T) + 4 < 32) {                                                         \
      AC[0] = ap[((T) + 4) * 4];                                                \
      AC[1] = ap[((T) + 4) * 4 + 1];                                            \
    }                                                                           \
  }

__global__ __launch_bounds__(256, 3) void k_gemm1(const float* __restrict__ x,
                                                  const char* __restrict__ w1t,
                                                  const float* __restrict__ dis,
                                                  unsigned short* __restrict__ h1s) {
  const int l = threadIdx.x & 63;
  const int wid = (blockIdx.x * 256 + threadIdx.x) >> 6;
  const int stripe = wid >> 1;
  const int R0 = stripe * 32;
  if (R0 >= NN) return;
  const int j0 = (wid & 1) * 4;       // column half: fragments j0..j0+3
  const int h = l >> 5;
  int ra = R0 + (l & 31);
  if (ra >= NN) ra = NN - 1;

  const float4* ap = (const float4*)(x + (size_t)ra * DIMK) + h * 2;
  const char* wb = w1t + j0 * 1024 + l * 16;

  f32x16 acc[4];
#pragma unroll
  for (int j = 0; j < 4; ++j)
#pragma unroll
    for (int g = 0; g < 16; ++g) acc[j][g] = 0.f;

  // prologue: A steps 0..3, B steps 0..1
  float4 A0[2], A1[2], A2[2], A3[2];
  A0[0] = ap[0];  A0[1] = ap[1];
  A1[0] = ap[4];  A1[1] = ap[5];
  A2[0] = ap[8];  A2[1] = ap[9];
  A3[0] = ap[12]; A3[1] = ap[13];
  s16x8 Ba[4], Bb[4];
#pragma unroll
  for (int j = 0; j < 4; ++j) Ba[j] = *(const s16x8*)(wb + j * 1024);
#pragma unroll
  for (int j = 0; j < 4; ++j) Bb[j] = *(const s16x8*)(wb + 8192 + j * 1024);

#pragma unroll
  for (int q = 0; q < 8; ++q) {
    GSTEP(4 * q + 0, A0, Ba);
    GSTEP(4 * q + 1, A1, Bb);
    GSTEP(4 * q + 2, A2, Ba);
    GSTEP(4 * q + 3, A3, Bb);
  }

  // epilogue: D col = (j0+j)*32 + (l&31), row = (reg&3) + 8*(reg>>2) + 4*(l>>5)
  const int cc = l & 31;
  float dv[16];
#pragma unroll
  for (int g = 0; g < 16; ++g) {
    int row = R0 + (g & 3) + 8 * (g >> 2) + 4 * h;
    dv[g] = (row < NN) ? dis[row] : 0.f;
  }
#pragma unroll
  for (int j = 0; j < 4; ++j) {
#pragma unroll
    for (int g = 0; g < 16; ++g) {
      int row = R0 + (g & 3) + 8 * (g >> 2) + 4 * h;
      if (row < NN)
        h1s[(size_t)row * HIDN + (j0 + j) * 32 + cc] = f2bf(acc[j][g] * dv[g]);
    }
  }
}

// ---------------- fused: aggregate h1s (CSR) + b1 + ReLU + @W2 -> h2s (pre-scaled) ----------------
__global__ __launch_bounds__(256) void k_agg1(const unsigned short* __restrict__ h1s,
                                              const int* __restrict__ offsets,
                                              const int* __restrict__ ssorted,
                                              const float* __restrict__ dis,
                                              const float* __restrict__ b1,
                                              const float* __restrict__ W2,
                                              float* __restrict__ h2s) {
  const int w = threadIdx.x >> 6;
  const int l = threadIdx.x & 63;
  const int d = blockIdx.x * 4 + w;
  if (d >= NN) return;

  float a0, a1, a2, a3;
  {                                    // self term
    uint2 v = *(const uint2*)(h1s + (size_t)d * HIDN + l * 4);
    a0 = __uint_as_float(v.x << 16);
    a1 = __uint_as_float(v.x & 0xffff0000u);
    a2 = __uint_as_float(v.y << 16);
    a3 = __uint_as_float(v.y & 0xffff0000u);
  }
  const int off0 = offsets[d], off1 = offsets[d + 1];
  int e = off0;
  for (; e + 4 <= off1; e += 4) {
    int s0 = ssorted[e], s1 = ssorted[e + 1], s2 = ssorted[e + 2], s3 = ssorted[e + 3];
    uint2 v0 = *(const uint2*)(h1s + (size_t)s0 * HIDN + l * 4);
    uint2 v1 = *(const uint2*)(h1s + (size_t)s1 * HIDN + l * 4);
    uint2 v2 = *(const uint2*)(h1s + (size_t)s2 * HIDN + l * 4);
    uint2 v3 = *(const uint2*)(h1s + (size_t)s3 * HIDN + l * 4);
    a0 += __uint_as_float(v0.x << 16) + __uint_as_float(v1.x << 16) +
          __uint_as_float(v2.x << 16) + __uint_as_float(v3.x << 16);
    a1 += __uint_as_float(v0.x & 0xffff0000u) + __uint_as_float(v1.x & 0xffff0000u) +
          __uint_as_float(v2.x & 0xffff0000u) + __uint_as_float(v3.x & 0xffff0000u);
    a2 += __uint_as_float(v0.y << 16) + __uint_as_float(v1.y << 16) +
          __uint_as_float(v2.y << 16) + __uint_as_float(v3.y << 16);
    a3 += __uint_as_float(v0.y & 0xffff0000u) + __uint_as_float(v1.y & 0xffff0000u) +
          __uint_as_float(v2.y & 0xffff0000u) + __uint_as_float(v3.y & 0xffff0000u);
  }
  for (; e < off1; ++e) {
    int s = ssorted[e];
    uint2 v = *(const uint2*)(h1s + (size_t)s * HIDN + l * 4);
    a0 += __uint_as_float(v.x << 16);
    a1 += __uint_as_float(v.x & 0xffff0000u);
    a2 += __uint_as_float(v.y << 16);
    a3 += __uint_as_float(v.y & 0xffff0000u);
  }

  const float dsd = dis[d];
  const int c0 = l * 4;
  float r0 = fmaxf(a0 * dsd + b1[c0 + 0], 0.f);
  float r1 = fmaxf(a1 * dsd + b1[c0 + 1], 0.f);
  float r2 = fmaxf(a2 * dsd + b1[c0 + 2], 0.f);
  float r3 = fmaxf(a3 * dsd + b1[c0 + 3], 0.f);

  float p0 = r0 * W2[(c0 + 0) * 2] + r1 * W2[(c0 + 1) * 2] +
             r2 * W2[(c0 + 2) * 2] + r3 * W2[(c0 + 3) * 2];
  float p1 = r0 * W2[(c0 + 0) * 2 + 1] + r1 * W2[(c0 + 1) * 2 + 1] +
             r2 * W2[(c0 + 2) * 2 + 1] + r3 * W2[(c0 + 3) * 2 + 1];
#pragma unroll
  for (int o = 1; o < 64; o <<= 1) {
    p0 += __shfl_xor(p0, o);
    p1 += __shfl_xor(p1, o);
  }
  if (l == 0) {
    h2s[(size_t)d * 2 + 0] = dsd * p0;   // pre-scaled by dis[d] for layer-2 gather
    h2s[(size_t)d * 2 + 1] = dsd * p1;
  }
}

// ---------------- layer-2 aggregation (2 cols) ----------------
__global__ void k_agg2(const float* __restrict__ h2s, const int* __restrict__ offsets,
                       const int* __restrict__ ssorted, const float* __restrict__ dis,
                       const float* __restrict__ b2, float* __restrict__ out) {
  int d = blockIdx.x * 256 + threadIdx.x;
  if (d >= NN) return;
  float2 sv = *(const float2*)(h2s + (size_t)d * 2);
  float a0 = sv.x, a1 = sv.y;
  int off0 = offsets[d], off1 = offsets[d + 1];
  int e = off0;
  for (; e + 4 <= off1; e += 4) {
    int s0 = ssorted[e], s1 = ssorted[e + 1], s2 = ssorted[e + 2], s3 = ssorted[e + 3];
    float2 v0 = *(const float2*)(h2s + (size_t)s0 * 2);
    float2 v1 = *(const float2*)(h2s + (size_t)s1 * 2);
    float2 v2 = *(const float2*)(h2s + (size_t)s2 * 2);
    float2 v3 = *(const float2*)(h2s + (size_t)s3 * 2);
    a0 += v0.x + v1.x + v2.x + v3.x;
    a1 += v0.y + v1.y + v2.y + v3.y;
  }
  for (; e < off1; ++e) {
    int s = ssorted[e];
    float2 v = *(const float2*)(h2s + (size_t)s * 2);
    a0 += v.x; a1 += v.y;
  }
  float dsd = dis[d];
  out[(size_t)d * 2 + 0] = dsd * a0 + b2[0];
  out[(size_t)d * 2 + 1] = dsd * a1 + b2[1];
}

extern "C" void kernel_launch(void* const* d_in, const int* in_sizes, int n_in,
                              void* d_out, int out_size, void* d_ws, size_t ws_size,
                              hipStream_t stream) {
  (void)in_sizes; (void)n_in; (void)out_size; (void)ws_size;
  const float* x   = (const float*)d_in[0];
  const float* W1  = (const float*)d_in[1];
  const float* b1  = (const float*)d_in[2];
  const float* W2  = (const float*)d_in[3];
  const float* b2  = (const float*)d_in[4];
  const int*   ei  = (const int*)d_in[5];
  const int* esrc = ei;
  const int* edst = ei + NE;
  float* out = (float*)d_out;

  char* ws = (char*)d_ws;
  // workspace layout (all 16B-aligned), total ~30.3 MB
  unsigned short* h1s = (unsigned short*)(ws + 0);          // 25,600,000 B
  char*  w1t     = ws + 25600000;                           //    262,144 B
  float* dis     = (float*)(ws + 25862144);                 //    200,000 B
  float* h2s     = (float*)(ws + 26062144);                 //    400,000 B
  int*   cnt     = (int*)(ws + 26462144);                   //    200,000 B
  int*   offsets = (int*)(ws + 26662144);                   //    200,004 B
  int*   cursor  = (int*)(ws + 26862208);                   //    200,000 B
  int*   ssorted = (int*)(ws + 27062208);                   //  3,200,000 B
  int*   blocksum= (int*)(ws + 30262208);                   //        196 B
  int*   blockoff= (int*)(ws + 30262464);                   //        196 B

  hipMemsetAsync(cnt, 0, NN * sizeof(int), stream);
  k_hist<<<(NE + 255) / 256, 256, 0, stream>>>(edst, cnt);
  k_blocksum<<<NBLK, 256, 0, stream>>>(cnt, blocksum);
  k_scanblocks<<<1, 64, 0, stream>>>(blocksum, blockoff);
  k_finalize<<<NBLK, 256, 0, stream>>>(cnt, blockoff, offsets, cursor, dis);
  k_scatter<<<(NE + 255) / 256, 256, 0, stream>>>(esrc, edst, cursor, ssorted);
  k_prep_w1t<<<(DIMK * HIDN) / 256, 256, 0, stream>>>(W1, w1t);
  {
    const int nwaves = 2 * ((NN + 31) / 32);        // 3126
    const int nblk   = (nwaves + 3) / 4;            // 782
    k_gemm1<<<nblk, 256, 0, stream>>>(x, w1t, dis, h1s);
  }
  k_agg1<<<(NN + 3) / 4, 256, 0, stream>>>(h1s, offsets, ssorted, dis, b1, W2, h2s);
  k_agg2<<<(NN + 255) / 256, 256, 0, stream>>>(h2s, offsets, ssorted, dis, b2, out);
}